// Round 1
// baseline (532.585 us; speedup 1.0000x reference)
//
#include <hip/hip_runtime.h>

#define V 50257
#define H 256
#define B 128
#define S 50
#define T 32
#define TQ 32

typedef __bf16 bf16x8 __attribute__((ext_vector_type(8)));
typedef float f32x4 __attribute__((ext_vector_type(4)));

__device__ inline unsigned short f2bf(float x) {
  __bf16 b = (__bf16)x;
  return __builtin_bit_cast(unsigned short, b);
}

// ---------- kernel 1: weight f32 -> bf16 conversion (6 matrices of 768x256) ----------
__global__ __launch_bounds__(256) void k_wconv(
    const float* w0, const float* w1, const float* w2,
    const float* w3, const float* w4, const float* w5,
    unsigned short* dst) {
  int mat = blockIdx.x / 192;
  int blk = blockIdx.x % 192;
  const float* src = (mat == 0) ? w0 : (mat == 1) ? w1 : (mat == 2) ? w2
                   : (mat == 3) ? w3 : (mat == 4) ? w4 : w5;
  int off = blk * 1024 + threadIdx.x * 4;
  float4 v = *(const float4*)(src + off);
  unsigned short* d = dst + mat * 196608 + off;
  d[0] = f2bf(v.x); d[1] = f2bf(v.y); d[2] = f2bf(v.z); d[3] = f2bf(v.w);
}

// ---------- kernel 2: embedding gather + position encoding ----------
__global__ __launch_bounds__(256) void k_embed(
    const int* ctx_idx, const int* q_idx, const float* emb,
    unsigned short* ctx_bf, unsigned short* q_bf) {
  __shared__ int sidx[T];
  int r = blockIdx.x;
  int tid = threadIdx.x;
  if (r < B * S) {
    if (tid < T) sidx[tid] = ctx_idx[r * T + tid];
    __syncthreads();
    float e = tid * (1.0f / 255.0f);
    float acc = 0.f;
    #pragma unroll 4
    for (int t = 0; t < T; ++t) {
      float tf = t * (1.0f / 31.0f);
      float w = (1.0f - tf) - e * (1.0f - 2.0f * tf);
      acc += emb[sidx[t] * H + tid] * w;
    }
    ctx_bf[r * H + tid] = f2bf(acc);
  } else {
    int rq = r - B * S;
    q_bf[rq * H + tid] = f2bf(emb[q_idx[rq] * H + tid]);
  }
}

// ---------- kernel 3: G = X(M,256)bf16 @ W(768,256)^T + bias -> f32 (M,768) ----------
__global__ __launch_bounds__(256) void k_gemm(
    const unsigned short* __restrict__ Xb, const unsigned short* __restrict__ Wb,
    const float* __restrict__ bias, float* __restrict__ Out) {
  const int n0 = blockIdx.x * 64;
  const int m0 = blockIdx.y * 128;
  __shared__ unsigned short lA[128 * 40];
  __shared__ unsigned short lB[64 * 40];
  int tid = threadIdx.x;
  int lane = tid & 63, wv = tid >> 6;
  int lr = lane & 15, lg = lane >> 4;
  f32x4 acc[2][4] = {};
  int sr = tid >> 2, skk = (tid & 3) * 8;
  for (int kt = 0; kt < 8; ++kt) {
    int k0 = kt * 32;
    __syncthreads();
    *(uint4*)&lA[sr * 40 + skk]        = *(const uint4*)&Xb[(m0 + sr) * 256 + k0 + skk];
    *(uint4*)&lA[(sr + 64) * 40 + skk] = *(const uint4*)&Xb[(m0 + sr + 64) * 256 + k0 + skk];
    *(uint4*)&lB[sr * 40 + skk]        = *(const uint4*)&Wb[(n0 + sr) * 256 + k0 + skk];
    __syncthreads();
    bf16x8 av0 = *(const bf16x8*)&lA[(wv * 32 + lr) * 40 + lg * 8];
    bf16x8 av1 = *(const bf16x8*)&lA[(wv * 32 + 16 + lr) * 40 + lg * 8];
    #pragma unroll
    for (int nt = 0; nt < 4; ++nt) {
      bf16x8 bv = *(const bf16x8*)&lB[(nt * 16 + lr) * 40 + lg * 8];
      acc[0][nt] = __builtin_amdgcn_mfma_f32_16x16x32_bf16(av0, bv, acc[0][nt], 0, 0, 0);
      acc[1][nt] = __builtin_amdgcn_mfma_f32_16x16x32_bf16(av1, bv, acc[1][nt], 0, 0, 0);
    }
  }
  #pragma unroll
  for (int nt = 0; nt < 4; ++nt) {
    int col = n0 + nt * 16 + lr;
    float bs = bias[col];
    #pragma unroll
    for (int mt = 0; mt < 2; ++mt) {
      #pragma unroll
      for (int r = 0; r < 4; ++r) {
        int row = m0 + wv * 32 + mt * 16 + lg * 4 + r;
        Out[row * 768 + col] = acc[mt][nt][r] + bs;
      }
    }
  }
}

// ---------- kernel 4: GRU recurrences (f, b, q). 24 blocks x 512 thr ----------
__global__ __launch_bounds__(512) void k_rnn(
    const float* __restrict__ Gf, const float* __restrict__ Gb, const float* __restrict__ Gq,
    const unsigned short* __restrict__ WhF, const unsigned short* __restrict__ WhB,
    const unsigned short* __restrict__ WhQ,
    const float* __restrict__ bhF, const float* __restrict__ bhB, const float* __restrict__ bhQ,
    float* __restrict__ outF, float* __restrict__ outB, float* __restrict__ qvec) {
  int blk = blockIdx.x;
  int mode = blk >> 3;   // 0=fwd, 1=bwd, 2=question
  int rg = blk & 7;      // batch rows [rg*16, rg*16+16)
  const float* G = (mode == 0) ? Gf : (mode == 1) ? Gb : Gq;
  const unsigned short* Wh = (mode == 0) ? WhF : (mode == 1) ? WhB : WhQ;
  const float* bh = (mode == 0) ? bhF : (mode == 1) ? bhB : bhQ;
  const int Tn = (mode == 2) ? TQ : S;
  const int SEQ = (mode == 2) ? TQ : S;
  float* ob = (mode == 0) ? outF : outB;

  __shared__ unsigned short hb[16 * 264];  // bf16 h, A-frag layout (row stride 264)
  __shared__ float hf[16 * 264];           // f32 master h

  int tid = threadIdx.x;
  for (int i = tid; i < 16 * 264; i += 512) { hb[i] = 0; hf[i] = 0.f; }
  int lane = tid & 63, wv = tid >> 6;      // wv 0..7
  int wcol = wv * 32;
  int lr = lane & 15, lg = lane >> 4;
  __syncthreads();

  for (int t = 0; t < Tn; ++t) {
    int s = (mode == 1) ? (S - 1 - t) : t;
    // load A-frags (h) for all 8 k-tiles
    bf16x8 af[8];
    #pragma unroll
    for (int kt = 0; kt < 8; ++kt)
      af[kt] = *(const bf16x8*)&hb[lr * 264 + kt * 32 + lg * 8];
    __syncthreads();  // everyone has read h before anyone overwrites

    f32x4 acc[6] = {};
    #pragma unroll
    for (int g = 0; g < 3; ++g) {
      #pragma unroll
      for (int nt = 0; nt < 2; ++nt) {
        int n = g * 256 + wcol + nt * 16 + lr;
        const unsigned short* wp = Wh + n * 256 + lg * 8;
        #pragma unroll
        for (int kt = 0; kt < 8; ++kt) {
          bf16x8 bv = *(const bf16x8*)(wp + kt * 32);
          acc[g * 2 + nt] = __builtin_amdgcn_mfma_f32_16x16x32_bf16(af[kt], bv, acc[g * 2 + nt], 0, 0, 0);
        }
      }
    }
    // gates + h update
    #pragma unroll
    for (int nt = 0; nt < 2; ++nt) {
      int j = wcol + nt * 16 + lr;
      float bhr = bh[j], bhz = bh[256 + j], bhn = bh[512 + j];
      #pragma unroll
      for (int r = 0; r < 4; ++r) {
        int m = lg * 4 + r;
        int grow = ((rg * 16 + m) * SEQ + s) * 768;
        float xr = G[grow + j];
        float xz = G[grow + 256 + j];
        float xn = G[grow + 512 + j];
        float hr = acc[0 + nt][r] + bhr;
        float hz = acc[2 + nt][r] + bhz;
        float hn = acc[4 + nt][r] + bhn;
        float rgate = 1.f / (1.f + expf(-(xr + hr)));
        float zgate = 1.f / (1.f + expf(-(xz + hz)));
        float ngate = tanhf(xn + rgate * hn);
        float hold = hf[m * 264 + j];
        float hnew = (1.f - zgate) * ngate + zgate * hold;
        hf[m * 264 + j] = hnew;
        hb[m * 264 + j] = f2bf(hnew);
        if (mode == 2) {
          if (t == TQ - 1) qvec[(rg * 16 + m) * H + j] = hnew;
        } else {
          ob[((rg * 16 + m) * S + s) * H + j] = hnew;
        }
      }
    }
    __syncthreads();  // writes visible before next step's A-frag loads
  }
}

// ---------- kernel 5: attention + memory read + tanh(q*read) ----------
__global__ __launch_bounds__(256) void k_attn(
    const float* __restrict__ outF, const float* __restrict__ outB,
    const float* __restrict__ qvec, unsigned short* __restrict__ tqv) {
  int b = blockIdx.x, tid = threadIdx.x;
  __shared__ float fs[S * H];
  __shared__ float qs[H];
  __shared__ float es[S];
  qs[tid] = qvec[b * H + tid];
  for (int s = 0; s < S; ++s)
    fs[s * H + tid] = outF[(b * S + s) * H + tid] + outB[(b * S + s) * H + tid];
  __syncthreads();
  int lane = tid & 63, wv = tid >> 6;
  for (int s = wv; s < S; s += 4) {
    const float* fr = &fs[s * H];
    float p = 0.f;
    #pragma unroll
    for (int j = 0; j < 4; ++j) p += fr[lane * 4 + j] * qs[lane * 4 + j];
    #pragma unroll
    for (int off = 32; off > 0; off >>= 1) p += __shfl_xor(p, off, 64);
    if (lane == 0) es[s] = p;
  }
  __syncthreads();
  float mx = -1e30f;
  for (int s = 0; s < S; ++s) mx = fmaxf(mx, es[s]);
  float sum = 0.f;
  for (int s = 0; s < S; ++s) sum += expf(es[s] - mx);
  float inv = 1.f / sum;
  float rd = 0.f;
  for (int s = 0; s < S; ++s) rd += expf(es[s] - mx) * inv * fs[s * H + tid];
  tqv[b * H + tid] = f2bf(tanhf(qs[tid] * rd));
}

// ---------- kernel 6: out = tanh(q*read)(128,256) @ Wo(V,256)^T + bo ----------
__global__ __launch_bounds__(256) void k_out(
    const unsigned short* __restrict__ tqv, const float* __restrict__ Wo,
    const float* __restrict__ bo, float* __restrict__ Out) {
  int n0 = blockIdx.x * 64;
  int tid = threadIdx.x, lane = tid & 63, wv = tid >> 6;
  int lr = lane & 15, lg = lane >> 4;
  __shared__ unsigned short lA[B * H];  // 64KB, XOR-swizzled rows
  #pragma unroll
  for (int i = 0; i < 16; ++i) {
    int c = tid + i * 256;
    int row = c >> 5, kk = (c & 31) * 8;
    int dst = row * 512 + ((kk * 2) ^ ((row & 7) << 4));
    *(uint4*)((char*)lA + dst) = *(const uint4*)&tqv[row * H + kk];
  }
  __syncthreads();
  int vcol = n0 + wv * 16 + lr;
  int vc = (vcol < V) ? vcol : (V - 1);
  f32x4 acc[8] = {};
  for (int kt = 0; kt < 8; ++kt) {
    const float* wp = &Wo[vc * H + kt * 32 + lg * 8];
    float4 w0 = *(const float4*)wp;
    float4 w1 = *(const float4*)(wp + 4);
    bf16x8 bv;
    bv[0] = (__bf16)w0.x; bv[1] = (__bf16)w0.y; bv[2] = (__bf16)w0.z; bv[3] = (__bf16)w0.w;
    bv[4] = (__bf16)w1.x; bv[5] = (__bf16)w1.y; bv[6] = (__bf16)w1.z; bv[7] = (__bf16)w1.w;
    #pragma unroll
    for (int mt = 0; mt < 8; ++mt) {
      int row = mt * 16 + lr;
      int boff = row * 512 + ((kt * 64 + lg * 16) ^ ((row & 7) << 4));
      bf16x8 av = *(const bf16x8*)((const char*)lA + boff);
      acc[mt] = __builtin_amdgcn_mfma_f32_16x16x32_bf16(av, bv, acc[mt], 0, 0, 0);
    }
  }
  if (vcol < V) {
    float bs = bo[vcol];
    #pragma unroll
    for (int mt = 0; mt < 8; ++mt)
      #pragma unroll
      for (int r = 0; r < 4; ++r) {
        int row = mt * 16 + lg * 4 + r;
        Out[row * V + vcol] = acc[mt][r] + bs;
      }
  }
}

extern "C" void kernel_launch(void* const* d_in, const int* in_sizes, int n_in,
                              void* d_out, int out_size, void* d_ws, size_t ws_size,
                              hipStream_t stream) {
  const int* contexts  = (const int*)d_in[0];
  const int* questions = (const int*)d_in[1];
  const float* emb   = (const float*)d_in[2];
  const float* Wih_f = (const float*)d_in[3];
  const float* Whh_f = (const float*)d_in[4];
  const float* bih_f = (const float*)d_in[5];
  const float* bhh_f = (const float*)d_in[6];
  const float* Wih_b = (const float*)d_in[7];
  const float* Whh_b = (const float*)d_in[8];
  const float* bih_b = (const float*)d_in[9];
  const float* bhh_b = (const float*)d_in[10];
  const float* Wih_q = (const float*)d_in[11];
  const float* Whh_q = (const float*)d_in[12];
  const float* bih_q = (const float*)d_in[13];
  const float* bhh_q = (const float*)d_in[14];
  const float* Wo = (const float*)d_in[15];
  const float* bo = (const float*)d_in[16];
  float* out = (float*)d_out;

  char* ws = (char*)d_ws;
  unsigned short* ctx_bf = (unsigned short*)(ws);             // 6400*256*2  = 3,276,800
  unsigned short* q_bf   = (unsigned short*)(ws + 3276800);   // 4096*256*2  = 2,097,152
  unsigned short* wbf    = (unsigned short*)(ws + 5373952);   // 6*196608*2  = 2,359,296
  unsigned short* WihF_b = wbf + 0 * 196608;
  unsigned short* WhhF_b = wbf + 1 * 196608;
  unsigned short* WihB_b = wbf + 2 * 196608;
  unsigned short* WhhB_b = wbf + 3 * 196608;
  unsigned short* WihQ_b = wbf + 4 * 196608;
  unsigned short* WhhQ_b = wbf + 5 * 196608;
  float* Gf   = (float*)(ws + 7733248);    // 6400*768*4 = 19,660,800
  float* Gb   = (float*)(ws + 27394048);   // 19,660,800
  float* Gq   = (float*)(ws + 47054848);   // 4096*768*4 = 12,582,912
  float* outFp = (float*)(ws + 59637760);  // 128*50*256*4 = 6,553,600
  float* outBp = (float*)(ws + 66191360);  // 6,553,600
  float* qvec = (float*)(ws + 72744960);   // 128*256*4 = 131,072
  unsigned short* tqv = (unsigned short*)(ws + 72876032);  // 65,536  (end ~69.6MB)

  k_wconv<<<1152, 256, 0, stream>>>(Wih_f, Whh_f, Wih_b, Whh_b, Wih_q, Whh_q, wbf);
  k_embed<<<B * S + B * TQ, 256, 0, stream>>>(contexts, questions, emb, ctx_bf, q_bf);
  k_gemm<<<dim3(12, 50), 256, 0, stream>>>(ctx_bf, WihF_b, bih_f, Gf);
  k_gemm<<<dim3(12, 50), 256, 0, stream>>>(ctx_bf, WihB_b, bih_b, Gb);
  k_gemm<<<dim3(12, 32), 256, 0, stream>>>(q_bf, WihQ_b, bih_q, Gq);
  k_rnn<<<24, 512, 0, stream>>>(Gf, Gb, Gq, WhhF_b, WhhB_b, WhhQ_b,
                                bhh_f, bhh_b, bhh_q, outFp, outBp, qvec);
  k_attn<<<B, 256, 0, stream>>>(outFp, outBp, qvec, tqv);
  k_out<<<786, 256, 0, stream>>>(tqv, Wo, bo, out);
}

// Round 2
// 485.233 us; speedup vs baseline: 1.0976x; 1.0976x over previous
//
#include <hip/hip_runtime.h>

#define V 50257
#define H 256
#define B 128
#define S 50
#define T 32
#define TQ 32

typedef __bf16 bf16x8 __attribute__((ext_vector_type(8)));
typedef float f32x4 __attribute__((ext_vector_type(4)));

__device__ inline unsigned short f2bf(float x) {
  __bf16 b = (__bf16)x;
  return __builtin_bit_cast(unsigned short, b);
}

__device__ inline float sigf(float x) {
  return 1.f / (1.f + __builtin_amdgcn_exp2f(-1.4426950408889634f * x));
}
__device__ inline float tanhfast(float x) {
  // 1 - 2/(exp2(2x*log2e)+1): saturates cleanly at +-1, no NaN at extremes
  return 1.f - 2.f / (__builtin_amdgcn_exp2f(2.8853900817779268f * x) + 1.f);
}

// ---------- kernel 1: weight f32 -> bf16 conversion (6 matrices of 768x256) ----------
__global__ __launch_bounds__(256) void k_wconv(
    const float* w0, const float* w1, const float* w2,
    const float* w3, const float* w4, const float* w5,
    unsigned short* dst) {
  int mat = blockIdx.x / 192;
  int blk = blockIdx.x % 192;
  const float* src = (mat == 0) ? w0 : (mat == 1) ? w1 : (mat == 2) ? w2
                   : (mat == 3) ? w3 : (mat == 4) ? w4 : w5;
  int off = blk * 1024 + threadIdx.x * 4;
  float4 v = *(const float4*)(src + off);
  unsigned short* d = dst + mat * 196608 + off;
  d[0] = f2bf(v.x); d[1] = f2bf(v.y); d[2] = f2bf(v.z); d[3] = f2bf(v.w);
}

// ---------- kernel 2: embedding gather + position encoding (wave-per-row, float4) ----------
__global__ __launch_bounds__(256) void k_embed(
    const int* __restrict__ ctx_idx, const int* __restrict__ q_idx,
    const float* __restrict__ emb,
    unsigned short* __restrict__ ctx_bf, unsigned short* __restrict__ q_bf) {
  int tid = threadIdx.x;
  int wv = tid >> 6, lane = tid & 63;
  int r = blockIdx.x * 4 + wv;
  if (r < B * S) {
    int myidx = ctx_idx[r * T + (lane & 31)];
    float e0 = (float)(lane * 4) * (1.f / 255.f);
    float4 acc = make_float4(0.f, 0.f, 0.f, 0.f);
    #pragma unroll 4
    for (int t = 0; t < T; ++t) {
      int id = __shfl(myidx, t, 64);
      float4 v = *(const float4*)&emb[(long)id * H + lane * 4];
      float tf = t * (1.f / 31.f);
      float a = 1.f - tf;
      float bb = 2.f * tf - 1.f;
      acc.x += (a + (e0 + 0.f * (1.f / 255.f)) * bb) * v.x;
      acc.y += (a + (e0 + 1.f * (1.f / 255.f)) * bb) * v.y;
      acc.z += (a + (e0 + 2.f * (1.f / 255.f)) * bb) * v.z;
      acc.w += (a + (e0 + 3.f * (1.f / 255.f)) * bb) * v.w;
    }
    ushort4 o;
    o.x = f2bf(acc.x); o.y = f2bf(acc.y); o.z = f2bf(acc.z); o.w = f2bf(acc.w);
    *(ushort4*)&ctx_bf[r * H + lane * 4] = o;
  } else {
    int rq = r - B * S;
    if (rq < B * TQ) {
      float4 v = *(const float4*)&emb[(long)q_idx[rq] * H + lane * 4];
      ushort4 o;
      o.x = f2bf(v.x); o.y = f2bf(v.y); o.z = f2bf(v.z); o.w = f2bf(v.w);
      *(ushort4*)&q_bf[rq * H + lane * 4] = o;
    }
  }
}

// ---------- kernel 3: G = X(M,256)bf16 @ W(768,256)^T + bias -> f32 (M,768) ----------
__global__ __launch_bounds__(256) void k_gemm(
    const unsigned short* __restrict__ Xb, const unsigned short* __restrict__ Wb,
    const float* __restrict__ bias, float* __restrict__ Out) {
  const int n0 = blockIdx.x * 64;
  const int m0 = blockIdx.y * 128;
  __shared__ unsigned short lA[128 * 40];
  __shared__ unsigned short lB[64 * 40];
  int tid = threadIdx.x;
  int lane = tid & 63, wv = tid >> 6;
  int lr = lane & 15, lg = lane >> 4;
  f32x4 acc[2][4] = {};
  int sr = tid >> 2, skk = (tid & 3) * 8;
  for (int kt = 0; kt < 8; ++kt) {
    int k0 = kt * 32;
    __syncthreads();
    *(uint4*)&lA[sr * 40 + skk]        = *(const uint4*)&Xb[(m0 + sr) * 256 + k0 + skk];
    *(uint4*)&lA[(sr + 64) * 40 + skk] = *(const uint4*)&Xb[(m0 + sr + 64) * 256 + k0 + skk];
    *(uint4*)&lB[sr * 40 + skk]        = *(const uint4*)&Wb[(n0 + sr) * 256 + k0 + skk];
    __syncthreads();
    bf16x8 av0 = *(const bf16x8*)&lA[(wv * 32 + lr) * 40 + lg * 8];
    bf16x8 av1 = *(const bf16x8*)&lA[(wv * 32 + 16 + lr) * 40 + lg * 8];
    #pragma unroll
    for (int nt = 0; nt < 4; ++nt) {
      bf16x8 bv = *(const bf16x8*)&lB[(nt * 16 + lr) * 40 + lg * 8];
      acc[0][nt] = __builtin_amdgcn_mfma_f32_16x16x32_bf16(av0, bv, acc[0][nt], 0, 0, 0);
      acc[1][nt] = __builtin_amdgcn_mfma_f32_16x16x32_bf16(av1, bv, acc[1][nt], 0, 0, 0);
    }
  }
  #pragma unroll
  for (int nt = 0; nt < 4; ++nt) {
    int col = n0 + nt * 16 + lr;
    float bs = bias[col];
    #pragma unroll
    for (int mt = 0; mt < 2; ++mt) {
      #pragma unroll
      for (int r = 0; r < 4; ++r) {
        int row = m0 + wv * 32 + mt * 16 + lg * 4 + r;
        Out[row * 768 + col] = acc[mt][nt][r] + bs;
      }
    }
  }
}

// ---------- kernel 4: GRU recurrences, persistent weights in registers ----------
// 24 blocks x 512 thr. Each block: 16 batch rows, full 768 gate outputs.
// Wave wv owns output cols [wv*32, wv*32+32) for all 3 gates -> 48 bf16x8 = 192 VGPRs.
// f32 master h lives in registers (lane updates the same (m,j) elems every step);
// bf16 h in LDS only for the cross-lane MFMA A-fragments.
__global__ __launch_bounds__(512, 2) void k_rnn(
    const float* __restrict__ Gf, const float* __restrict__ Gb, const float* __restrict__ Gq,
    const unsigned short* __restrict__ WhF, const unsigned short* __restrict__ WhB,
    const unsigned short* __restrict__ WhQ,
    const float* __restrict__ bhF, const float* __restrict__ bhB, const float* __restrict__ bhQ,
    float* __restrict__ outF, float* __restrict__ outB, float* __restrict__ qvec) {
  int blk = blockIdx.x;
  int mode = blk >> 3;   // 0=fwd, 1=bwd, 2=question
  int rg = blk & 7;      // batch rows [rg*16, rg*16+16)
  const float* G = (mode == 0) ? Gf : (mode == 1) ? Gb : Gq;
  const unsigned short* Wh = (mode == 0) ? WhF : (mode == 1) ? WhB : WhQ;
  const float* bh = (mode == 0) ? bhF : (mode == 1) ? bhB : bhQ;
  const int Tn = (mode == 2) ? TQ : S;
  const int SEQ = Tn;
  float* ob = (mode == 0) ? outF : outB;

  __shared__ unsigned short hb[16 * 264];  // bf16 h, row stride 264 (2-way-free banks)

  int tid = threadIdx.x;
  int lane = tid & 63, wv = tid >> 6;
  int lr = lane & 15, lg = lane >> 4;

  for (int i = tid; i < 16 * 264; i += 512) hb[i] = 0;

  // persistent weight fragments: w[g][nt][kt]
  bf16x8 w[3][2][8];
  #pragma unroll
  for (int g = 0; g < 3; ++g)
    #pragma unroll
    for (int nt = 0; nt < 2; ++nt) {
      const unsigned short* wp = Wh + (g * 256 + wv * 32 + nt * 16 + lr) * 256 + lg * 8;
      #pragma unroll
      for (int kt = 0; kt < 8; ++kt)
        w[g][nt][kt] = *(const bf16x8*)(wp + kt * 32);
    }

  float bhv[3][2];
  #pragma unroll
  for (int g = 0; g < 3; ++g)
    #pragma unroll
    for (int nt = 0; nt < 2; ++nt)
      bhv[g][nt] = bh[g * 256 + wv * 32 + nt * 16 + lr];

  float hcur[2][4] = {};  // f32 master h for this lane's 8 (m,j) elements

  __syncthreads();

  for (int t = 0; t < Tn; ++t) {
    int s = (mode == 1) ? (S - 1 - t) : t;
    f32x4 acc[6] = {};
    #pragma unroll
    for (int kt = 0; kt < 8; ++kt) {
      bf16x8 a = *(const bf16x8*)&hb[lr * 264 + kt * 32 + lg * 8];
      #pragma unroll
      for (int g = 0; g < 3; ++g) {
        acc[g * 2 + 0] = __builtin_amdgcn_mfma_f32_16x16x32_bf16(a, w[g][0][kt], acc[g * 2 + 0], 0, 0, 0);
        acc[g * 2 + 1] = __builtin_amdgcn_mfma_f32_16x16x32_bf16(a, w[g][1][kt], acc[g * 2 + 1], 0, 0, 0);
      }
    }
    // gate math (h master in registers; no LDS access here)
    #pragma unroll
    for (int nt = 0; nt < 2; ++nt) {
      int j = wv * 32 + nt * 16 + lr;
      #pragma unroll
      for (int r = 0; r < 4; ++r) {
        int m = lg * 4 + r;
        long grow = (long)((rg * 16 + m) * SEQ + s) * 768;
        float xr = G[grow + j];
        float xz = G[grow + 256 + j];
        float xn = G[grow + 512 + j];
        float rr = sigf(xr + acc[0 + nt][r] + bhv[0][nt]);
        float zz = sigf(xz + acc[2 + nt][r] + bhv[1][nt]);
        float nn = tanhfast(xn + rr * (acc[4 + nt][r] + bhv[2][nt]));
        hcur[nt][r] = (1.f - zz) * nn + zz * hcur[nt][r];
      }
    }
    __syncthreads();  // all waves done reading hb for this step
    #pragma unroll
    for (int nt = 0; nt < 2; ++nt) {
      int j = wv * 32 + nt * 16 + lr;
      #pragma unroll
      for (int r = 0; r < 4; ++r) {
        int m = lg * 4 + r;
        hb[m * 264 + j] = f2bf(hcur[nt][r]);
        if (mode != 2)
          ob[(long)((rg * 16 + m) * S + s) * H + j] = hcur[nt][r];
      }
    }
    __syncthreads();  // writes visible before next step's reads
  }

  if (mode == 2) {
    #pragma unroll
    for (int nt = 0; nt < 2; ++nt) {
      int j = wv * 32 + nt * 16 + lr;
      #pragma unroll
      for (int r = 0; r < 4; ++r) {
        int m = lg * 4 + r;
        qvec[(rg * 16 + m) * H + j] = hcur[nt][r];
      }
    }
  }
}

// ---------- kernel 5: attention + memory read + tanh(q*read) ----------
__global__ __launch_bounds__(256) void k_attn(
    const float* __restrict__ outF, const float* __restrict__ outB,
    const float* __restrict__ qvec, unsigned short* __restrict__ tqv) {
  int b = blockIdx.x, tid = threadIdx.x;
  __shared__ float fs[S * H];
  __shared__ float qs[H];
  __shared__ float es[S];
  qs[tid] = qvec[b * H + tid];
  for (int s = 0; s < S; ++s)
    fs[s * H + tid] = outF[(b * S + s) * H + tid] + outB[(b * S + s) * H + tid];
  __syncthreads();
  int lane = tid & 63, wv = tid >> 6;
  for (int s = wv; s < S; s += 4) {
    const float* fr = &fs[s * H];
    float p = 0.f;
    #pragma unroll
    for (int j = 0; j < 4; ++j) p += fr[lane * 4 + j] * qs[lane * 4 + j];
    #pragma unroll
    for (int off = 32; off > 0; off >>= 1) p += __shfl_xor(p, off, 64);
    if (lane == 0) es[s] = p;
  }
  __syncthreads();
  float mx = -1e30f;
  for (int s = 0; s < S; ++s) mx = fmaxf(mx, es[s]);
  float sum = 0.f;
  for (int s = 0; s < S; ++s) sum += expf(es[s] - mx);
  float inv = 1.f / sum;
  float rd = 0.f;
  for (int s = 0; s < S; ++s) rd += expf(es[s] - mx) * inv * fs[s * H + tid];
  tqv[b * H + tid] = f2bf(tanhf(qs[tid] * rd));
}

// ---------- kernel 6: out = tanh(q*read)(128,256) @ Wo(V,256)^T + bo ----------
__global__ __launch_bounds__(256) void k_out(
    const unsigned short* __restrict__ tqv, const float* __restrict__ Wo,
    const float* __restrict__ bo, float* __restrict__ Out) {
  int n0 = blockIdx.x * 64;
  int tid = threadIdx.x, lane = tid & 63, wv = tid >> 6;
  int lr = lane & 15, lg = lane >> 4;
  __shared__ unsigned short lA[B * H];  // 64KB, XOR-swizzled rows
  #pragma unroll
  for (int i = 0; i < 16; ++i) {
    int c = tid + i * 256;
    int row = c >> 5, kk = (c & 31) * 8;
    int dst = row * 512 + ((kk * 2) ^ ((row & 7) << 4));
    *(uint4*)((char*)lA + dst) = *(const uint4*)&tqv[row * H + kk];
  }
  __syncthreads();
  int vcol = n0 + wv * 16 + lr;
  int vc = (vcol < V) ? vcol : (V - 1);
  f32x4 acc[8] = {};
  for (int kt = 0; kt < 8; ++kt) {
    const float* wp = &Wo[vc * H + kt * 32 + lg * 8];
    float4 w0 = *(const float4*)wp;
    float4 w1 = *(const float4*)(wp + 4);
    bf16x8 bv;
    bv[0] = (__bf16)w0.x; bv[1] = (__bf16)w0.y; bv[2] = (__bf16)w0.z; bv[3] = (__bf16)w0.w;
    bv[4] = (__bf16)w1.x; bv[5] = (__bf16)w1.y; bv[6] = (__bf16)w1.z; bv[7] = (__bf16)w1.w;
    #pragma unroll
    for (int mt = 0; mt < 8; ++mt) {
      int row = mt * 16 + lr;
      int boff = row * 512 + ((kt * 64 + lg * 16) ^ ((row & 7) << 4));
      bf16x8 av = *(const bf16x8*)((const char*)lA + boff);
      acc[mt] = __builtin_amdgcn_mfma_f32_16x16x32_bf16(av, bv, acc[mt], 0, 0, 0);
    }
  }
  if (vcol < V) {
    float bs = bo[vcol];
    #pragma unroll
    for (int mt = 0; mt < 8; ++mt)
      #pragma unroll
      for (int r = 0; r < 4; ++r) {
        int row = mt * 16 + lg * 4 + r;
        Out[row * V + vcol] = acc[mt][r] + bs;
      }
  }
}

extern "C" void kernel_launch(void* const* d_in, const int* in_sizes, int n_in,
                              void* d_out, int out_size, void* d_ws, size_t ws_size,
                              hipStream_t stream) {
  const int* contexts  = (const int*)d_in[0];
  const int* questions = (const int*)d_in[1];
  const float* emb   = (const float*)d_in[2];
  const float* Wih_f = (const float*)d_in[3];
  const float* Whh_f = (const float*)d_in[4];
  const float* bih_f = (const float*)d_in[5];
  const float* bhh_f = (const float*)d_in[6];
  const float* Wih_b = (const float*)d_in[7];
  const float* Whh_b = (const float*)d_in[8];
  const float* bih_b = (const float*)d_in[9];
  const float* bhh_b = (const float*)d_in[10];
  const float* Wih_q = (const float*)d_in[11];
  const float* Whh_q = (const float*)d_in[12];
  const float* bih_q = (const float*)d_in[13];
  const float* bhh_q = (const float*)d_in[14];
  const float* Wo = (const float*)d_in[15];
  const float* bo = (const float*)d_in[16];
  float* out = (float*)d_out;

  char* ws = (char*)d_ws;
  unsigned short* ctx_bf = (unsigned short*)(ws);             // 6400*256*2  = 3,276,800
  unsigned short* q_bf   = (unsigned short*)(ws + 3276800);   // 4096*256*2  = 2,097,152
  unsigned short* wbf    = (unsigned short*)(ws + 5373952);   // 6*196608*2  = 2,359,296
  unsigned short* WihF_b = wbf + 0 * 196608;
  unsigned short* WhhF_b = wbf + 1 * 196608;
  unsigned short* WihB_b = wbf + 2 * 196608;
  unsigned short* WhhB_b = wbf + 3 * 196608;
  unsigned short* WihQ_b = wbf + 4 * 196608;
  unsigned short* WhhQ_b = wbf + 5 * 196608;
  float* Gf   = (float*)(ws + 7733248);    // 6400*768*4 = 19,660,800
  float* Gb   = (float*)(ws + 27394048);   // 19,660,800
  float* Gq   = (float*)(ws + 47054848);   // 4096*768*4 = 12,582,912
  float* outFp = (float*)(ws + 59637760);  // 128*50*256*4 = 6,553,600
  float* outBp = (float*)(ws + 66191360);  // 6,553,600
  float* qvec = (float*)(ws + 72744960);   // 128*256*4 = 131,072
  unsigned short* tqv = (unsigned short*)(ws + 72876032);  // 65,536

  k_wconv<<<1152, 256, 0, stream>>>(Wih_f, Whh_f, Wih_b, Whh_b, Wih_q, Whh_q, wbf);
  k_embed<<<(B * S + B * TQ + 3) / 4, 256, 0, stream>>>(contexts, questions, emb, ctx_bf, q_bf);
  k_gemm<<<dim3(12, 50), 256, 0, stream>>>(ctx_bf, WihF_b, bih_f, Gf);
  k_gemm<<<dim3(12, 50), 256, 0, stream>>>(ctx_bf, WihB_b, bih_b, Gb);
  k_gemm<<<dim3(12, 32), 256, 0, stream>>>(q_bf, WihQ_b, bih_q, Gq);
  k_rnn<<<24, 512, 0, stream>>>(Gf, Gb, Gq, WhhF_b, WhhB_b, WhhQ_b,
                                bhh_f, bhh_b, bhh_q, outFp, outBp, qvec);
  k_attn<<<B, 256, 0, stream>>>(outFp, outBp, qvec, tqv);
  k_out<<<786, 256, 0, stream>>>(tqv, Wo, bo, out);
}

// Round 3
// 426.180 us; speedup vs baseline: 1.2497x; 1.1386x over previous
//
#include <hip/hip_runtime.h>

#define V 50257
#define H 256
#define B 128
#define S 50
#define T 32
#define TQ 32

typedef __bf16 bf16x8 __attribute__((ext_vector_type(8)));
typedef float f32x4 __attribute__((ext_vector_type(4)));

__device__ inline unsigned short f2bf(float x) {
  __bf16 b = (__bf16)x;
  return __builtin_bit_cast(unsigned short, b);
}

__device__ inline float sigf(float x) {
  return 1.f / (1.f + __builtin_amdgcn_exp2f(-1.4426950408889634f * x));
}
__device__ inline float tanhfast(float x) {
  return 1.f - 2.f / (__builtin_amdgcn_exp2f(2.8853900817779268f * x) + 1.f);
}

// ---------- kernel 1: weight f32 -> bf16 conversion (6 matrices of 768x256) ----------
__global__ __launch_bounds__(256) void k_wconv(
    const float* w0, const float* w1, const float* w2,
    const float* w3, const float* w4, const float* w5,
    unsigned short* dst) {
  int mat = blockIdx.x / 192;
  int blk = blockIdx.x % 192;
  const float* src = (mat == 0) ? w0 : (mat == 1) ? w1 : (mat == 2) ? w2
                   : (mat == 3) ? w3 : (mat == 4) ? w4 : w5;
  int off = blk * 1024 + threadIdx.x * 4;
  float4 v = *(const float4*)(src + off);
  unsigned short* d = dst + mat * 196608 + off;
  d[0] = f2bf(v.x); d[1] = f2bf(v.y); d[2] = f2bf(v.z); d[3] = f2bf(v.w);
}

// ---------- kernel 2: embedding gather + position encoding (wave-per-row, float4) ----------
__global__ __launch_bounds__(256) void k_embed(
    const int* __restrict__ ctx_idx, const int* __restrict__ q_idx,
    const float* __restrict__ emb,
    unsigned short* __restrict__ ctx_bf, unsigned short* __restrict__ q_bf) {
  int tid = threadIdx.x;
  int wv = tid >> 6, lane = tid & 63;
  int r = blockIdx.x * 4 + wv;
  if (r < B * S) {
    int myidx = ctx_idx[r * T + (lane & 31)];
    float e0 = (float)(lane * 4) * (1.f / 255.f);
    float4 acc = make_float4(0.f, 0.f, 0.f, 0.f);
    #pragma unroll 4
    for (int t = 0; t < T; ++t) {
      int id = __shfl(myidx, t, 64);
      float4 v = *(const float4*)&emb[(long)id * H + lane * 4];
      float tf = t * (1.f / 31.f);
      float a = 1.f - tf;
      float bb = 2.f * tf - 1.f;
      acc.x += (a + (e0 + 0.f * (1.f / 255.f)) * bb) * v.x;
      acc.y += (a + (e0 + 1.f * (1.f / 255.f)) * bb) * v.y;
      acc.z += (a + (e0 + 2.f * (1.f / 255.f)) * bb) * v.z;
      acc.w += (a + (e0 + 3.f * (1.f / 255.f)) * bb) * v.w;
    }
    ushort4 o;
    o.x = f2bf(acc.x); o.y = f2bf(acc.y); o.z = f2bf(acc.z); o.w = f2bf(acc.w);
    *(ushort4*)&ctx_bf[r * H + lane * 4] = o;
  } else {
    int rq = r - B * S;
    if (rq < B * TQ) {
      float4 v = *(const float4*)&emb[(long)q_idx[rq] * H + lane * 4];
      ushort4 o;
      o.x = f2bf(v.x); o.y = f2bf(v.y); o.z = f2bf(v.z); o.w = f2bf(v.w);
      *(ushort4*)&q_bf[rq * H + lane * 4] = o;
    }
  }
}

// ---------- kernel 3: G = X(M,256)bf16 @ W(768,256)^T + bias -> f32, TRANSPOSED out ----------
// X rows are (b-major, seq-minor): r = b*seq + s. Output stored [s][b][768] so the
// recurrence reads a contiguous slab per step.
__global__ __launch_bounds__(256) void k_gemm(
    const unsigned short* __restrict__ Xb, const unsigned short* __restrict__ Wb,
    const float* __restrict__ bias, float* __restrict__ Out, int seq) {
  const int n0 = blockIdx.x * 64;
  const int m0 = blockIdx.y * 128;
  __shared__ unsigned short lA[128 * 40];
  __shared__ unsigned short lB[64 * 40];
  int tid = threadIdx.x;
  int lane = tid & 63, wv = tid >> 6;
  int lr = lane & 15, lg = lane >> 4;
  f32x4 acc[2][4] = {};
  int sr = tid >> 2, skk = (tid & 3) * 8;
  for (int kt = 0; kt < 8; ++kt) {
    int k0 = kt * 32;
    __syncthreads();
    *(uint4*)&lA[sr * 40 + skk]        = *(const uint4*)&Xb[(m0 + sr) * 256 + k0 + skk];
    *(uint4*)&lA[(sr + 64) * 40 + skk] = *(const uint4*)&Xb[(m0 + sr + 64) * 256 + k0 + skk];
    *(uint4*)&lB[sr * 40 + skk]        = *(const uint4*)&Wb[(n0 + sr) * 256 + k0 + skk];
    __syncthreads();
    bf16x8 av0 = *(const bf16x8*)&lA[(wv * 32 + lr) * 40 + lg * 8];
    bf16x8 av1 = *(const bf16x8*)&lA[(wv * 32 + 16 + lr) * 40 + lg * 8];
    #pragma unroll
    for (int nt = 0; nt < 4; ++nt) {
      bf16x8 bv = *(const bf16x8*)&lB[(nt * 16 + lr) * 40 + lg * 8];
      acc[0][nt] = __builtin_amdgcn_mfma_f32_16x16x32_bf16(av0, bv, acc[0][nt], 0, 0, 0);
      acc[1][nt] = __builtin_amdgcn_mfma_f32_16x16x32_bf16(av1, bv, acc[1][nt], 0, 0, 0);
    }
  }
  #pragma unroll
  for (int nt = 0; nt < 4; ++nt) {
    int col = n0 + nt * 16 + lr;
    float bs = bias[col];
    #pragma unroll
    for (int mt = 0; mt < 2; ++mt) {
      #pragma unroll
      for (int r = 0; r < 4; ++r) {
        int row = m0 + wv * 32 + mt * 16 + lg * 4 + r;
        int bidx = row / seq;
        int ss = row - bidx * seq;
        Out[(long)(ss * B + bidx) * 768 + col] = acc[mt][nt][r] + bs;
      }
    }
  }
}

// ---------- kernel 4: GRU recurrences, weights pinned in registers ----------
// 24 blocks x 512 thr. Block: 16 batch rows, full 768 gate outputs.
// Wave wv owns cols [wv*32, wv*32+32) x 3 gates -> 48 x 128-bit frags = 192 VGPRs,
// pinned via asm anti-remat + waves_per_eu(2,2) (256-VGPR budget).
__global__ __launch_bounds__(512)
__attribute__((amdgpu_waves_per_eu(2, 2)))
void k_rnn(
    const float* __restrict__ Gf, const float* __restrict__ Gb, const float* __restrict__ Gq,
    const unsigned short* __restrict__ WhF, const unsigned short* __restrict__ WhB,
    const unsigned short* __restrict__ WhQ,
    const float* __restrict__ bhF, const float* __restrict__ bhB, const float* __restrict__ bhQ,
    float* __restrict__ outF, float* __restrict__ outB, float* __restrict__ qvec) {
  int blk = blockIdx.x;
  int mode = blk >> 3;   // 0=fwd, 1=bwd, 2=question
  int rg = blk & 7;      // batch rows [rg*16, rg*16+16)
  const float* G = (mode == 0) ? Gf : (mode == 1) ? Gb : Gq;
  const unsigned short* Wh = (mode == 0) ? WhF : (mode == 1) ? WhB : WhQ;
  const float* bh = (mode == 0) ? bhF : (mode == 1) ? bhB : bhQ;
  const int Tn = (mode == 2) ? TQ : S;
  float* ob = (mode == 0) ? outF : outB;

  __shared__ unsigned short hb[2][16 * 264];  // bf16 h double-buffer

  int tid = threadIdx.x;
  int lane = tid & 63, wv = tid >> 6;
  int lr = lane & 15, lg = lane >> 4;

  for (int i = tid; i < 16 * 264; i += 512) { hb[0][i] = 0; hb[1][i] = 0; }

  // persistent weight fragments, pinned: w[g*16 + nt*8 + kt]
  f32x4 w[48];
  #pragma unroll
  for (int g = 0; g < 3; ++g)
    #pragma unroll
    for (int nt = 0; nt < 2; ++nt) {
      const unsigned short* wp = Wh + (g * 256 + wv * 32 + nt * 16 + lr) * 256 + lg * 8;
      #pragma unroll
      for (int kt = 0; kt < 8; ++kt)
        w[g * 16 + nt * 8 + kt] = *(const f32x4*)(wp + kt * 32);
    }
  #pragma unroll
  for (int i = 0; i < 48; ++i) asm volatile("" : "+v"(w[i]));

  float bhv[3][2];
  #pragma unroll
  for (int g = 0; g < 3; ++g)
    #pragma unroll
    for (int nt = 0; nt < 2; ++nt)
      bhv[g][nt] = bh[g * 256 + wv * 32 + nt * 16 + lr];

  float hcur[2][4] = {};
  int cur = 0;
  __syncthreads();

  for (int t = 0; t < Tn; ++t) {
    int s = (mode == 1) ? (S - 1 - t) : t;
    const float* Gs = G + (long)s * (128 * 768);
    f32x4 acc[6] = {};
    #pragma unroll
    for (int kt = 0; kt < 8; ++kt) {
      bf16x8 a = *(const bf16x8*)&hb[cur][lr * 264 + kt * 32 + lg * 8];
      #pragma unroll
      for (int g = 0; g < 3; ++g) {
        acc[g * 2 + 0] = __builtin_amdgcn_mfma_f32_16x16x32_bf16(
            a, __builtin_bit_cast(bf16x8, w[g * 16 + kt]), acc[g * 2 + 0], 0, 0, 0);
        acc[g * 2 + 1] = __builtin_amdgcn_mfma_f32_16x16x32_bf16(
            a, __builtin_bit_cast(bf16x8, w[g * 16 + 8 + kt]), acc[g * 2 + 1], 0, 0, 0);
      }
    }
    // gates (h master in registers)
    #pragma unroll
    for (int nt = 0; nt < 2; ++nt) {
      int j = wv * 32 + nt * 16 + lr;
      #pragma unroll
      for (int r = 0; r < 4; ++r) {
        int m = lg * 4 + r;
        long grow = (long)(rg * 16 + m) * 768;
        float xr = Gs[grow + j];
        float xz = Gs[grow + 256 + j];
        float xn = Gs[grow + 512 + j];
        float rr = sigf(xr + acc[0 + nt][r] + bhv[0][nt]);
        float zz = sigf(xz + acc[2 + nt][r] + bhv[1][nt]);
        float nn = tanhfast(xn + rr * (acc[4 + nt][r] + bhv[2][nt]));
        hcur[nt][r] = (1.f - zz) * nn + zz * hcur[nt][r];
      }
    }
    // write next h buffer + sequence output
    #pragma unroll
    for (int nt = 0; nt < 2; ++nt) {
      int j = wv * 32 + nt * 16 + lr;
      #pragma unroll
      for (int r = 0; r < 4; ++r) {
        int m = lg * 4 + r;
        hb[cur ^ 1][m * 264 + j] = f2bf(hcur[nt][r]);
        if (mode != 2)
          ob[(long)(s * B + rg * 16 + m) * H + j] = hcur[nt][r];
      }
    }
    __syncthreads();
    cur ^= 1;
  }

  if (mode == 2) {
    #pragma unroll
    for (int nt = 0; nt < 2; ++nt) {
      int j = wv * 32 + nt * 16 + lr;
      #pragma unroll
      for (int r = 0; r < 4; ++r) {
        int m = lg * 4 + r;
        qvec[(rg * 16 + m) * H + j] = hcur[nt][r];
      }
    }
  }
}

// ---------- kernel 5: attention + memory read + tanh(q*read) ----------
__global__ __launch_bounds__(256) void k_attn(
    const float* __restrict__ outF, const float* __restrict__ outB,
    const float* __restrict__ qvec, unsigned short* __restrict__ tqv) {
  int b = blockIdx.x, tid = threadIdx.x;
  __shared__ float fs[S * H];
  __shared__ float qs[H];
  __shared__ float es[S];
  qs[tid] = qvec[b * H + tid];
  for (int s = 0; s < S; ++s)
    fs[s * H + tid] = outF[(long)(s * B + b) * H + tid] + outB[(long)(s * B + b) * H + tid];
  __syncthreads();
  int lane = tid & 63, wv = tid >> 6;
  for (int s = wv; s < S; s += 4) {
    const float* fr = &fs[s * H];
    float p = 0.f;
    #pragma unroll
    for (int j = 0; j < 4; ++j) p += fr[lane * 4 + j] * qs[lane * 4 + j];
    #pragma unroll
    for (int off = 32; off > 0; off >>= 1) p += __shfl_xor(p, off, 64);
    if (lane == 0) es[s] = p;
  }
  __syncthreads();
  float mx = -1e30f;
  for (int s = 0; s < S; ++s) mx = fmaxf(mx, es[s]);
  float sum = 0.f;
  for (int s = 0; s < S; ++s) sum += expf(es[s] - mx);
  float inv = 1.f / sum;
  float rd = 0.f;
  for (int s = 0; s < S; ++s) rd += expf(es[s] - mx) * inv * fs[s * H + tid];
  tqv[b * H + tid] = f2bf(tanhf(qs[tid] * rd));
}

// ---------- kernel 6: out = tanh(q*read)(128,256) @ Wo(V,256)^T + bo ----------
__global__ __launch_bounds__(256) void k_out(
    const unsigned short* __restrict__ tqv, const float* __restrict__ Wo,
    const float* __restrict__ bo, float* __restrict__ Out) {
  int n0 = blockIdx.x * 64;
  int tid = threadIdx.x, lane = tid & 63, wv = tid >> 6;
  int lr = lane & 15, lg = lane >> 4;
  __shared__ unsigned short lA[B * H];  // 64KB, XOR-swizzled rows
  #pragma unroll
  for (int i = 0; i < 16; ++i) {
    int c = tid + i * 256;
    int row = c >> 5, kk = (c & 31) * 8;
    int dst = row * 512 + ((kk * 2) ^ ((row & 7) << 4));
    *(uint4*)((char*)lA + dst) = *(const uint4*)&tqv[row * H + kk];
  }
  __syncthreads();
  int vcol = n0 + wv * 16 + lr;
  int vc = (vcol < V) ? vcol : (V - 1);
  f32x4 acc[8] = {};
  for (int kt = 0; kt < 8; ++kt) {
    const float* wp = &Wo[vc * H + kt * 32 + lg * 8];
    float4 w0 = *(const float4*)wp;
    float4 w1 = *(const float4*)(wp + 4);
    bf16x8 bv;
    bv[0] = (__bf16)w0.x; bv[1] = (__bf16)w0.y; bv[2] = (__bf16)w0.z; bv[3] = (__bf16)w0.w;
    bv[4] = (__bf16)w1.x; bv[5] = (__bf16)w1.y; bv[6] = (__bf16)w1.z; bv[7] = (__bf16)w1.w;
    #pragma unroll
    for (int mt = 0; mt < 8; ++mt) {
      int row = mt * 16 + lr;
      int boff = row * 512 + ((kt * 64 + lg * 16) ^ ((row & 7) << 4));
      bf16x8 av = *(const bf16x8*)((const char*)lA + boff);
      acc[mt] = __builtin_amdgcn_mfma_f32_16x16x32_bf16(av, bv, acc[mt], 0, 0, 0);
    }
  }
  if (vcol < V) {
    float bs = bo[vcol];
    #pragma unroll
    for (int mt = 0; mt < 8; ++mt)
      #pragma unroll
      for (int r = 0; r < 4; ++r) {
        int row = mt * 16 + lg * 4 + r;
        Out[row * V + vcol] = acc[mt][r] + bs;
      }
  }
}

extern "C" void kernel_launch(void* const* d_in, const int* in_sizes, int n_in,
                              void* d_out, int out_size, void* d_ws, size_t ws_size,
                              hipStream_t stream) {
  const int* contexts  = (const int*)d_in[0];
  const int* questions = (const int*)d_in[1];
  const float* emb   = (const float*)d_in[2];
  const float* Wih_f = (const float*)d_in[3];
  const float* Whh_f = (const float*)d_in[4];
  const float* bih_f = (const float*)d_in[5];
  const float* bhh_f = (const float*)d_in[6];
  const float* Wih_b = (const float*)d_in[7];
  const float* Whh_b = (const float*)d_in[8];
  const float* bih_b = (const float*)d_in[9];
  const float* bhh_b = (const float*)d_in[10];
  const float* Wih_q = (const float*)d_in[11];
  const float* Whh_q = (const float*)d_in[12];
  const float* bih_q = (const float*)d_in[13];
  const float* bhh_q = (const float*)d_in[14];
  const float* Wo = (const float*)d_in[15];
  const float* bo = (const float*)d_in[16];
  float* out = (float*)d_out;

  char* ws = (char*)d_ws;
  unsigned short* ctx_bf = (unsigned short*)(ws);             // 3,276,800
  unsigned short* q_bf   = (unsigned short*)(ws + 3276800);   // 2,097,152
  unsigned short* wbf    = (unsigned short*)(ws + 5373952);   // 2,359,296
  unsigned short* WihF_b = wbf + 0 * 196608;
  unsigned short* WhhF_b = wbf + 1 * 196608;
  unsigned short* WihB_b = wbf + 2 * 196608;
  unsigned short* WhhB_b = wbf + 3 * 196608;
  unsigned short* WihQ_b = wbf + 4 * 196608;
  unsigned short* WhhQ_b = wbf + 5 * 196608;
  float* Gf   = (float*)(ws + 7733248);    // 19,660,800  [s][b][768]
  float* Gb   = (float*)(ws + 27394048);   // 19,660,800
  float* Gq   = (float*)(ws + 47054848);   // 12,582,912  [t][b][768]
  float* outFp = (float*)(ws + 59637760);  // 6,553,600   [s][b][256]
  float* outBp = (float*)(ws + 66191360);  // 6,553,600
  float* qvec = (float*)(ws + 72744960);   // 131,072
  unsigned short* tqv = (unsigned short*)(ws + 72876032);  // 65,536

  k_wconv<<<1152, 256, 0, stream>>>(Wih_f, Whh_f, Wih_b, Whh_b, Wih_q, Whh_q, wbf);
  k_embed<<<(B * S + B * TQ + 3) / 4, 256, 0, stream>>>(contexts, questions, emb, ctx_bf, q_bf);
  k_gemm<<<dim3(12, 50), 256, 0, stream>>>(ctx_bf, WihF_b, bih_f, Gf, S);
  k_gemm<<<dim3(12, 50), 256, 0, stream>>>(ctx_bf, WihB_b, bih_b, Gb, S);
  k_gemm<<<dim3(12, 32), 256, 0, stream>>>(q_bf, WihQ_b, bih_q, Gq, TQ);
  k_rnn<<<24, 512, 0, stream>>>(Gf, Gb, Gq, WhhF_b, WhhB_b, WhhQ_b,
                                bhh_f, bhh_b, bhh_q, outFp, outBp, qvec);
  k_attn<<<B, 256, 0, stream>>>(outFp, outBp, qvec, tqv);
  k_out<<<786, 256, 0, stream>>>(tqv, Wo, bo, out);
}